// Round 15
// baseline (1417.126 us; speedup 1.0000x reference)
//
#include <hip/hip_runtime.h>
#include <hip/hip_cooperative_groups.h>

namespace cg = cooperative_groups;

#define NNODES 50000
#define NEDGES 800000
#define NGRAPHS 64
#define INCH 128
#define HID 256
#define ZSTR (HID + 2)
#define SCAN_B 512
#define SCAN_NB ((NNODES + SCAN_B - 1) / SCAN_B)   // 98
#define NSLICE 16
#define NT64 ((NNODES + 63) / 64)                  // 782 tiles of 64 rows

typedef __attribute__((ext_vector_type(8))) short short8v;
typedef __attribute__((ext_vector_type(8))) unsigned short ushort8v;
typedef __attribute__((ext_vector_type(4))) float f32x4;

__device__ inline ushort f2b(float f) {
    union { float f; unsigned u; } v; v.f = f;
    unsigned r = (v.u + 0x7FFFu + ((v.u >> 16) & 1u)) >> 16;
    return (ushort)r;
}
__device__ inline float b2f(ushort b) {
    union { unsigned u; float f; } v; v.u = ((unsigned)b) << 16;
    return v.f;
}

// ---------------- degree + within-node position in ONE atomic pass ----------------
__global__ __launch_bounds__(256) void fill_pre(const int* __restrict__ dst, int* __restrict__ deg,
                                                unsigned char* __restrict__ pwn) {
    int e = blockIdx.x * 256 + threadIdx.x;
    if (e < NEDGES) pwn[e] = (unsigned char)atomicAdd(&deg[dst[e]], 1);
}

__global__ __launch_bounds__(256) void dis_kernel(const int* __restrict__ deg, float* __restrict__ dis) {
    int i = blockIdx.x * 256 + threadIdx.x;
    if (i < NNODES) dis[i] = rsqrtf((float)deg[i] + 1.0f);
}

// ---------------- scan (row_ptr from deg) ----------------
__global__ __launch_bounds__(SCAN_B) void scan1(const int* __restrict__ deg, int* __restrict__ row_ptr,
                                                int* __restrict__ bsum) {
    __shared__ int s[SCAN_B];
    int t = threadIdx.x;
    int i = blockIdx.x * SCAN_B + t;
    int v = (i < NNODES) ? deg[i] : 0;
    s[t] = v;
    __syncthreads();
    for (int off = 1; off < SCAN_B; off <<= 1) {
        int x = (t >= off) ? s[t - off] : 0;
        __syncthreads();
        if (t >= off) s[t] += x;
        __syncthreads();
    }
    if (i < NNODES) row_ptr[i + 1] = s[t];
    if (t == SCAN_B - 1) bsum[blockIdx.x] = s[t];
}

__global__ __launch_bounds__(128) void scan2(int* __restrict__ bsum) {
    __shared__ int s[128];
    int t = threadIdx.x;
    int v = (t < SCAN_NB) ? bsum[t] : 0;
    s[t] = v;
    __syncthreads();
    for (int off = 1; off < 128; off <<= 1) {
        int x = (t >= off) ? s[t - off] : 0;
        __syncthreads();
        if (t >= off) s[t] += x;
        __syncthreads();
    }
    if (t < SCAN_NB) bsum[t] = s[t];
}

__global__ __launch_bounds__(SCAN_B) void scan3(int* __restrict__ row_ptr, const int* __restrict__ bsum) {
    int b = blockIdx.x, t = threadIdx.x;
    int i = b * SCAN_B + t;
    if (i == 0) row_ptr[0] = 0;
    if (i < NNODES && b > 0) row_ptr[i + 1] += bsum[b - 1];
}

// ---------------- atomic-free CSR scatter, single pass, ushort payload ----------------
__global__ __launch_bounds__(256) void fill_scatter(const int* __restrict__ src, const int* __restrict__ dst,
                                                    const unsigned char* __restrict__ pwn,
                                                    const int* __restrict__ row_ptr,
                                                    ushort* __restrict__ csr_src) {
    int e = blockIdx.x * 256 + threadIdx.x;
    if (e >= NEDGES) return;
    int d = dst[e];
    csr_src[row_ptr[d] + pwn[e]] = (ushort)src[e];
}

// ---------------- x' = dis * x -> bf16 ----------------
__global__ __launch_bounds__(256) void xcvt(const float4* __restrict__ x, const float* __restrict__ dis,
                                            ushort4* __restrict__ xb, int n4) {
    int i = blockIdx.x * 256 + threadIdx.x;
    if (i >= n4) return;
    float d = dis[i >> 5];   // 32 float4 per node (128 ch)
    float4 v = x[i];
    ushort4 o;
    o.x = f2b(d * v.x); o.y = f2b(d * v.y); o.z = f2b(d * v.z); o.w = f2b(d * v.w);
    xb[i] = o;
}

// W[K x N] fp32 -> Wt[N x K] bf16
__global__ __launch_bounds__(256) void wcvt(const float* __restrict__ W, ushort* __restrict__ Wt, int K, int N) {
    int i = blockIdx.x * 256 + threadIdx.x;
    if (i >= K * N) return;
    int k = i / N, n = i - k * N;
    Wt[n * K + k] = f2b(W[i]);
}

// ---------------- persistent pipelined GCN: agg units + gemm units, per-tile flags ----------------
// agg unit t: S rows [64t,64t+64) = gather-sum over hin (pre-scaled by dis), store to global S.
template <int K>
__device__ void agg_unit(int t, const ushort* __restrict__ hin, const int* __restrict__ row_ptr,
                         const ushort* __restrict__ csr_src, ushort* __restrict__ S) {
    constexpr int CHL = K / 8;        // lanes per node
    constexpr int NPW = 64 / CHL;     // nodes per wave pass
    const int tid = threadIdx.x;
    const int w = tid >> 6, l = tid & 63;
    const int sub = l / CHL;
    const int lane = l - sub * CHL;
    const ushort* hp = hin + lane * 8;
#pragma unroll
    for (int it = 0; it < 64 / (4 * NPW); ++it) {
        int node = t * 64 + (it * 4 + w) * NPW + sub;
        if (node >= NNODES) continue;
        ushort8v sv = *(const ushort8v*)&hp[(size_t)node * K];
        float a0 = b2f(sv[0]), a1 = b2f(sv[1]), a2 = b2f(sv[2]), a3 = b2f(sv[3]);
        float a4 = b2f(sv[4]), a5 = b2f(sv[5]), a6 = b2f(sv[6]), a7 = b2f(sv[7]);
        int e = row_ptr[node], e1 = row_ptr[node + 1];
        for (; e + 7 < e1; e += 8) {
            ushort8v v[8];
#pragma unroll
            for (int u = 0; u < 8; ++u) v[u] = *(const ushort8v*)&hp[(size_t)csr_src[e + u] * K];
#pragma unroll
            for (int u = 0; u < 8; ++u) {
                a0 += b2f(v[u][0]); a1 += b2f(v[u][1]); a2 += b2f(v[u][2]); a3 += b2f(v[u][3]);
                a4 += b2f(v[u][4]); a5 += b2f(v[u][5]); a6 += b2f(v[u][6]); a7 += b2f(v[u][7]);
            }
        }
        for (; e < e1; ++e) {
            ushort8v v0 = *(const ushort8v*)&hp[(size_t)csr_src[e] * K];
            a0 += b2f(v0[0]); a1 += b2f(v0[1]); a2 += b2f(v0[2]); a3 += b2f(v0[3]);
            a4 += b2f(v0[4]); a5 += b2f(v0[5]); a6 += b2f(v0[6]); a7 += b2f(v0[7]);
        }
        ushort8v o;
        o[0] = f2b(a0); o[1] = f2b(a1); o[2] = f2b(a2); o[3] = f2b(a3);
        o[4] = f2b(a4); o[5] = f2b(a5); o[6] = f2b(a6); o[7] = f2b(a7);
        *(ushort8v*)&S[(size_t)node * K + lane * 8] = o;
    }
}

// gemm unit t: hout rows [64t,64t+64) = relu(dis*(S@W)+b)[*dis], 4 waves x 64 cols, acc[4][4]/wave.
template <int K>
__device__ void gemm_unit(int t, const ushort* __restrict__ S, const ushort* __restrict__ Bt,
                          const float* __restrict__ bias, const float* __restrict__ dis,
                          ushort* __restrict__ hout, int scale_out) {
    const int tid = threadIdx.x;
    const int w = tid >> 6, l = tid & 63;
    const int r16 = l & 15, kg = l >> 4;
    const int R = t * 64;
    const int Cb = w * 64;
    f32x4 acc[4][4] = {};
    for (int k0 = 0; k0 < K; k0 += 32) {
        int k = k0 + kg * 8;
        short8v a[4], b[4];
#pragma unroll
        for (int m = 0; m < 4; ++m) {
            int row = R + m * 16 + r16;
            if (row > NNODES - 1) row = NNODES - 1;
            a[m] = *(const short8v*)&S[(size_t)row * K + k];
        }
#pragma unroll
        for (int n = 0; n < 4; ++n)
            b[n] = *(const short8v*)&Bt[(size_t)(Cb + n * 16 + r16) * K + k];
#pragma unroll
        for (int m = 0; m < 4; ++m)
#pragma unroll
            for (int n = 0; n < 4; ++n)
                acc[m][n] = __builtin_amdgcn_mfma_f32_16x16x32_bf16(a[m], b[n], acc[m][n], 0, 0, 0);
    }
    float bv[4];
#pragma unroll
    for (int n = 0; n < 4; ++n) bv[n] = bias[Cb + n * 16 + r16];
#pragma unroll
    for (int m = 0; m < 4; ++m) {
#pragma unroll
        for (int j = 0; j < 4; ++j) {
            int row = R + m * 16 + kg * 4 + j;
            if (row >= NNODES) continue;
            float dr = dis[row];
            float os = scale_out ? dr : 1.0f;
#pragma unroll
            for (int n = 0; n < 4; ++n) {
                float v = fmaxf(dr * acc[m][n][j] + bv[n], 0.f) * os;
                hout[(size_t)row * HID + Cb + n * 16 + r16] = f2b(v);
            }
        }
    }
}

template <int K>
__device__ void layer_run(const ushort* hin, ushort* hout, const ushort* Bt, const float* bias,
                          const float* dis, const int* row_ptr, const ushort* csr_src, ushort* S,
                          int* ctr, int* flag, int scale_out) {
    __shared__ int s_u;
    for (;;) {
        __syncthreads();
        if (threadIdx.x == 0) s_u = atomicAdd(ctr, 1);
        __syncthreads();
        int u = s_u;
        if (u >= 2 * NT64) return;
        if (u < NT64) {
            agg_unit<K>(u, hin, row_ptr, csr_src, S);
            __threadfence();      // make S stores device-visible (wb L2)
            __syncthreads();      // all threads' stores+fence complete
            if (threadIdx.x == 0)
                __hip_atomic_store(&flag[u], 1, __ATOMIC_RELEASE, __HIP_MEMORY_SCOPE_AGENT);
        } else {
            int tt = u - NT64;
            if (threadIdx.x == 0) {
                while (__hip_atomic_load(&flag[tt], __ATOMIC_ACQUIRE, __HIP_MEMORY_SCOPE_AGENT) == 0)
                    __builtin_amdgcn_s_sleep(2);
            }
            __syncthreads();
            __threadfence();      // acquire: invalidate stale cached S lines
            gemm_unit<K>(tt, S, Bt, bias, dis, hout, scale_out);
        }
    }
}

__global__ __launch_bounds__(256, 4) void gcn_pipe(const ushort* __restrict__ xb, ushort* __restrict__ h,
                                                   ushort* __restrict__ hb, ushort* __restrict__ S,
                                                   const int* __restrict__ row_ptr,
                                                   const ushort* __restrict__ csr_src,
                                                   const ushort* __restrict__ Wt0,
                                                   const ushort* __restrict__ Wt1,
                                                   const ushort* __restrict__ Wt2,
                                                   const float* __restrict__ b0, const float* __restrict__ b1,
                                                   const float* __restrict__ b2, const float* __restrict__ dis,
                                                   int* __restrict__ ctrs, int* __restrict__ flags) {
    cg::grid_group grid = cg::this_grid();
    layer_run<INCH>(xb, h, Wt0, b0, dis, row_ptr, csr_src, S, ctrs + 0, flags, 1);
    __threadfence();
    grid.sync();
    __threadfence();
    layer_run<HID>(h, hb, Wt1, b1, dis, row_ptr, csr_src, S, ctrs + 1, flags + NT64, 1);
    __threadfence();
    grid.sync();
    __threadfence();
    layer_run<HID>(hb, h, Wt2, b2, dis, row_ptr, csr_src, S, ctrs + 2, flags + 2 * NT64, 0);
}

// ---------------- graph boundaries from sorted batch ----------------
__global__ __launch_bounds__(256) void graph_bounds(const int* __restrict__ batch, int* __restrict__ gstart) {
    int i = blockIdx.x * 256 + threadIdx.x;
    if (i >= NNODES) return;
    int b = batch[i];
    if (i == 0) {
        for (int g = 0; g <= b; ++g) gstart[g] = 0;
    } else {
        int pb = batch[i - 1];
        for (int g = pb + 1; g <= b; ++g) gstart[g] = i;
    }
    if (i == NNODES - 1) {
        for (int g = b + 1; g <= NGRAPHS; ++g) gstart[g] = NNODES;
    }
}

// ---------------- mean pool: sliced, atomic partial sums (h is bf16) ----------------
__global__ __launch_bounds__(HID) void pool_partial(const ushort* __restrict__ h, const int* __restrict__ gstart,
                                                    float* __restrict__ z) {
    int g = blockIdx.x;
    int s = blockIdx.y;
    int t = threadIdx.x;
    int n0 = gstart[g], n1 = gstart[g + 1];
    int cnt = n1 - n0;
    if (cnt <= 0) return;
    int len = (cnt + NSLICE - 1) / NSLICE;
    int a = n0 + s * len;
    int b = a + len < n1 ? a + len : n1;
    if (a >= b) return;
    float acc = 0.f;
    for (int n = a; n < b; ++n) acc += b2f(h[(size_t)n * HID + t]);
    atomicAdd(&z[g * ZSTR + t], acc);
}

__global__ __launch_bounds__(HID) void pool_finalize(const int* __restrict__ gstart, const float* __restrict__ hlr,
                                                     const float* __restrict__ stdv, float* __restrict__ z) {
    int g = blockIdx.x;
    int t = threadIdx.x;
    int cnt = gstart[g + 1] - gstart[g];
    float inv = 1.f / (float)(cnt > 0 ? cnt : 1);
    z[g * ZSTR + t] *= inv;
    if (t == 0) {
        z[g * ZSTR + HID] = hlr[g];
        z[g * ZSTR + HID + 1] = stdv[g];
    }
}

// ---------------- FC head: relu(z @ fcW0 + fcb0) @ fcW1 + fcb1 ----------------
__global__ __launch_bounds__(HID) void fc_k(const float* __restrict__ z, const float* __restrict__ fcW0,
                                            const float* __restrict__ fcb0, const float* __restrict__ fcW1,
                                            const float* __restrict__ fcb1, float* __restrict__ out) {
    __shared__ float zs[ZSTR];
    __shared__ float z2[HID];
    int g = blockIdx.x;
    int t = threadIdx.x;
    zs[t] = z[g * ZSTR + t];
    if (t < 2) zs[HID + t] = z[g * ZSTR + HID + t];
    __syncthreads();
    float acc = fcb0[t];
    for (int k = 0; k < ZSTR; ++k) acc += zs[k] * fcW0[k * HID + t];
    z2[t] = fmaxf(acc, 0.f);
    __syncthreads();
    if (t < INCH) {
        float acc2 = fcb1[t];
        for (int k = 0; k < HID; ++k) acc2 += z2[k] * fcW1[k * INCH + t];
        out[g * INCH + t] = acc2;
    }
}

extern "C" void kernel_launch(void* const* d_in, const int* in_sizes, int n_in,
                              void* d_out, int out_size, void* d_ws, size_t ws_size,
                              hipStream_t stream) {
    const float* x = (const float*)d_in[0];
    const int* ei = (const int*)d_in[1];
    const int* src = ei;
    const int* dst = ei + NEDGES;
    const int* batch = (const int*)d_in[2];
    const float* hlr = (const float*)d_in[3];
    const float* stdv = (const float*)d_in[4];
    const float* W0 = (const float*)d_in[5];
    const float* b0 = (const float*)d_in[6];
    const float* W1 = (const float*)d_in[7];
    const float* b1 = (const float*)d_in[8];
    const float* W2 = (const float*)d_in[9];
    const float* b2 = (const float*)d_in[10];
    const float* fcW0 = (const float*)d_in[11];
    const float* fcb0 = (const float*)d_in[12];
    const float* fcW1 = (const float*)d_in[13];
    const float* fcb1 = (const float*)d_in[14];
    float* out = (float*)d_out;

    char* p = (char*)d_ws;
    auto alloc = [&](size_t bytes) -> char* {
        char* r = p;
        p += (bytes + 255) & ~(size_t)255;
        return r;
    };
    ushort* xb = (ushort*)alloc(sizeof(ushort) * (size_t)NNODES * INCH);
    ushort* h = (ushort*)alloc(sizeof(ushort) * (size_t)NNODES * HID);
    ushort* hb = (ushort*)alloc(sizeof(ushort) * (size_t)NNODES * HID);
    ushort* S = (ushort*)alloc(sizeof(ushort) * (size_t)NNODES * HID);
    ushort* Wt0 = (ushort*)alloc(sizeof(ushort) * HID * INCH);
    ushort* Wt1 = (ushort*)alloc(sizeof(ushort) * HID * HID);
    ushort* Wt2 = (ushort*)alloc(sizeof(ushort) * HID * HID);
    float* dis = (float*)alloc(sizeof(float) * NNODES);
    int* deg = (int*)alloc(sizeof(int) * NNODES);
    int* row_ptr = (int*)alloc(sizeof(int) * (NNODES + 1));
    unsigned char* pwn = (unsigned char*)alloc(sizeof(unsigned char) * NEDGES);
    ushort* csr_src = (ushort*)alloc(sizeof(ushort) * NEDGES);
    int* bsum = (int*)alloc(sizeof(int) * 128);
    int* gstart = (int*)alloc(sizeof(int) * (NGRAPHS + 1));
    float* z = (float*)alloc(sizeof(float) * NGRAPHS * ZSTR);
    int* ctrs = (int*)alloc(sizeof(int) * 4);
    int* flags = (int*)alloc(sizeof(int) * NT64 * 3);
    (void)ws_size; (void)in_sizes; (void)n_in; (void)out_size;

    const int eblocks = (NEDGES + 255) / 256;

    hipMemsetAsync(deg, 0, sizeof(int) * NNODES, stream);
    hipMemsetAsync(ctrs, 0, sizeof(int) * 4, stream);
    hipMemsetAsync(flags, 0, sizeof(int) * NT64 * 3, stream);
    fill_pre<<<eblocks, 256, 0, stream>>>(dst, deg, pwn);
    dis_kernel<<<(NNODES + 255) / 256, 256, 0, stream>>>(deg, dis);
    scan1<<<SCAN_NB, SCAN_B, 0, stream>>>(deg, row_ptr, bsum);
    scan2<<<1, 128, 0, stream>>>(bsum);
    scan3<<<SCAN_NB, SCAN_B, 0, stream>>>(row_ptr, bsum);
    fill_scatter<<<eblocks, 256, 0, stream>>>(src, dst, pwn, row_ptr, csr_src);

    // conversions (x' = dis * x)
    xcvt<<<(NNODES * INCH / 4 + 255) / 256, 256, 0, stream>>>((const float4*)x, dis, (ushort4*)xb,
                                                              NNODES * INCH / 4);
    wcvt<<<(INCH * HID + 255) / 256, 256, 0, stream>>>(W0, Wt0, INCH, HID);
    wcvt<<<(HID * HID + 255) / 256, 256, 0, stream>>>(W1, Wt1, HID, HID);
    wcvt<<<(HID * HID + 255) / 256, 256, 0, stream>>>(W2, Wt2, HID, HID);

    // persistent cooperative pipeline: all 3 layers, agg/gemm overlapped via per-tile flags
    int nb = 0;
    hipOccupancyMaxActiveBlocksPerMultiprocessor(&nb, gcn_pipe, 256, 0);
    if (nb < 1) nb = 1;
    int grid = nb * 256;
    if (grid > 1024) grid = 1024;
    {
        void* args[] = {(void*)&xb, (void*)&h, (void*)&hb, (void*)&S, (void*)&row_ptr, (void*)&csr_src,
                        (void*)&Wt0, (void*)&Wt1, (void*)&Wt2, (void*)&b0, (void*)&b1, (void*)&b2,
                        (void*)&dis, (void*)&ctrs, (void*)&flags};
        hipLaunchCooperativeKernel((void*)gcn_pipe, dim3(grid), dim3(256), args, 0, stream);
    }

    graph_bounds<<<(NNODES + 255) / 256, 256, 0, stream>>>(batch, gstart);
    hipMemsetAsync(z, 0, sizeof(float) * NGRAPHS * ZSTR, stream);
    dim3 pgrid(NGRAPHS, NSLICE);
    pool_partial<<<pgrid, HID, 0, stream>>>(h, gstart, z);
    pool_finalize<<<NGRAPHS, HID, 0, stream>>>(gstart, hlr, stdv, z);
    fc_k<<<NGRAPHS, HID, 0, stream>>>(z, fcW0, fcb0, fcW1, fcb1, out);
}

// Round 16
// 382.483 us; speedup vs baseline: 3.7051x; 3.7051x over previous
//
#include <hip/hip_runtime.h>

#define NNODES 50000
#define NEDGES 800000
#define NGRAPHS 64
#define INCH 128
#define HID 256
#define ZSTR (HID + 2)
#define SCAN_B 512
#define SCAN_NB ((NNODES + SCAN_B - 1) / SCAN_B)   // 98
#define NSLICE 16

typedef __attribute__((ext_vector_type(8))) short short8v;
typedef __attribute__((ext_vector_type(8))) unsigned short ushort8v;
typedef __attribute__((ext_vector_type(4))) float f32x4;

__device__ inline ushort f2b(float f) {
    union { float f; unsigned u; } v; v.f = f;
    unsigned r = (v.u + 0x7FFFu + ((v.u >> 16) & 1u)) >> 16;
    return (ushort)r;
}
__device__ inline float b2f(ushort b) {
    union { unsigned u; float f; } v; v.u = ((unsigned)b) << 16;
    return v.f;
}

// ---------------- degree + within-node position in ONE atomic pass ----------------
// pwn fits uchar: max degree over Poisson(16) draws << 255.
__global__ __launch_bounds__(256) void fill_pre(const int* __restrict__ dst, int* __restrict__ deg,
                                                unsigned char* __restrict__ pwn) {
    int e = blockIdx.x * 256 + threadIdx.x;
    if (e < NEDGES) pwn[e] = (unsigned char)atomicAdd(&deg[dst[e]], 1);
}

__global__ __launch_bounds__(256) void dis_kernel(const int* __restrict__ deg, float* __restrict__ dis) {
    int i = blockIdx.x * 256 + threadIdx.x;
    if (i < NNODES) dis[i] = rsqrtf((float)deg[i] + 1.0f);
}

// ---------------- scan (row_ptr from deg) ----------------
__global__ __launch_bounds__(SCAN_B) void scan1(const int* __restrict__ deg, int* __restrict__ row_ptr,
                                                int* __restrict__ bsum) {
    __shared__ int s[SCAN_B];
    int t = threadIdx.x;
    int i = blockIdx.x * SCAN_B + t;
    int v = (i < NNODES) ? deg[i] : 0;
    s[t] = v;
    __syncthreads();
    for (int off = 1; off < SCAN_B; off <<= 1) {
        int x = (t >= off) ? s[t - off] : 0;
        __syncthreads();
        if (t >= off) s[t] += x;
        __syncthreads();
    }
    if (i < NNODES) row_ptr[i + 1] = s[t];
    if (t == SCAN_B - 1) bsum[blockIdx.x] = s[t];
}

__global__ __launch_bounds__(128) void scan2(int* __restrict__ bsum) {
    __shared__ int s[128];
    int t = threadIdx.x;
    int v = (t < SCAN_NB) ? bsum[t] : 0;
    s[t] = v;
    __syncthreads();
    for (int off = 1; off < 128; off <<= 1) {
        int x = (t >= off) ? s[t - off] : 0;
        __syncthreads();
        if (t >= off) s[t] += x;
        __syncthreads();
    }
    if (t < SCAN_NB) bsum[t] = s[t];
}

__global__ __launch_bounds__(SCAN_B) void scan3(int* __restrict__ row_ptr, const int* __restrict__ bsum) {
    int b = blockIdx.x, t = threadIdx.x;
    int i = b * SCAN_B + t;
    if (i == 0) row_ptr[0] = 0;
    if (i < NNODES && b > 0) row_ptr[i + 1] += bsum[b - 1];
}

// ---------------- atomic-free CSR scatter, single pass, ushort payload ----------------
__global__ __launch_bounds__(256) void fill_scatter(const int* __restrict__ src, const int* __restrict__ dst,
                                                    const unsigned char* __restrict__ pwn,
                                                    const int* __restrict__ row_ptr,
                                                    ushort* __restrict__ csr_src) {
    int e = blockIdx.x * 256 + threadIdx.x;
    if (e >= NEDGES) return;
    int d = dst[e];
    csr_src[row_ptr[d] + pwn[e]] = (ushort)src[e];
}

// ---------------- x' = dis * x -> bf16 ----------------
__global__ __launch_bounds__(256) void xcvt(const float4* __restrict__ x, const float* __restrict__ dis,
                                            ushort4* __restrict__ xb, int n4) {
    int i = blockIdx.x * 256 + threadIdx.x;
    if (i >= n4) return;
    float d = dis[i >> 5];   // 32 float4 per node (128 ch)
    float4 v = x[i];
    ushort4 o;
    o.x = f2b(d * v.x); o.y = f2b(d * v.y); o.z = f2b(d * v.z); o.w = f2b(d * v.w);
    xb[i] = o;
}

// W[K x N] fp32 -> Wt[N x K] bf16
__global__ __launch_bounds__(256) void wcvt(const float* __restrict__ W, ushort* __restrict__ Wt, int K, int N) {
    int i = blockIdx.x * 256 + threadIdx.x;
    if (i >= K * N) return;
    int k = i / N, n = i - k * N;
    Wt[n * K + k] = f2b(W[i]);
}

// ---------------- fused GCN layer: gather-sum into LDS, then MFMA GEMM + epilogue ----------------
// BM=64 rows/block, 512 threads (8 waves). Wave w -> rows [(w&1)*32, +32) x cols [(w>>1)*64, +64),
// acc[2][4] = 32 acc-regs/thread -> <=85 VGPR total -> 6 waves/SIMD -> 3 blocks/CU (LDS 32KB each).
// More resident blocks = cross-block gather/MFMA overlap (the gather-rate <-> occupancy lever).
// hout_r = relu(dis_r * (S @ W)_r + bias) * (scale_out ? dis_r : 1),  S_r = hin_r + sum_{j->r} hin_j
template <int K>
__global__ __launch_bounds__(512, 6) void gcn_fused(const ushort* __restrict__ hin,
                                                    const int* __restrict__ row_ptr,
                                                    const ushort* __restrict__ csr_src,
                                                    const ushort* __restrict__ Bt,
                                                    const float* __restrict__ bias,
                                                    const float* __restrict__ dis,
                                                    ushort* __restrict__ hout, int scale_out) {
    __shared__ ushort As[64 * K];   // XOR-swizzled: 16B granule g of row r lives at g^(r&7)
    const int tid = threadIdx.x;
    const int w = tid >> 6, l = tid & 63;
    const int R0 = blockIdx.x * 64;

    // ---- phase A: gather-sum 64 rows into LDS ----
    constexpr int CHL = K / 8;        // lanes per node (8 ch each): 32 (K=256) / 16 (K=128)
    constexpr int NPW = 64 / CHL;     // nodes per wave pass: 2 / 4
    const int sub = l / CHL;
    const int lane = l - sub * CHL;
    const ushort* hp = hin + lane * 8;
#pragma unroll
    for (int it = 0; it < 64 / (8 * NPW); ++it) {
        int nloc = (it * 8 + w) * NPW + sub;
        int node = R0 + nloc;
        ushort8v o;
        if (node < NNODES) {
            ushort8v sv = *(const ushort8v*)&hp[(size_t)node * K];
            float a0 = b2f(sv[0]), a1 = b2f(sv[1]), a2 = b2f(sv[2]), a3 = b2f(sv[3]);
            float a4 = b2f(sv[4]), a5 = b2f(sv[5]), a6 = b2f(sv[6]), a7 = b2f(sv[7]);
            int e = row_ptr[node], e1 = row_ptr[node + 1];
            for (; e + 7 < e1; e += 8) {
                ushort8v v[8];
#pragma unroll
                for (int u = 0; u < 8; ++u) v[u] = *(const ushort8v*)&hp[(size_t)csr_src[e + u] * K];
#pragma unroll
                for (int u = 0; u < 8; ++u) {
                    a0 += b2f(v[u][0]); a1 += b2f(v[u][1]); a2 += b2f(v[u][2]); a3 += b2f(v[u][3]);
                    a4 += b2f(v[u][4]); a5 += b2f(v[u][5]); a6 += b2f(v[u][6]); a7 += b2f(v[u][7]);
                }
            }
            for (; e < e1; ++e) {
                ushort8v v0 = *(const ushort8v*)&hp[(size_t)csr_src[e] * K];
                a0 += b2f(v0[0]); a1 += b2f(v0[1]); a2 += b2f(v0[2]); a3 += b2f(v0[3]);
                a4 += b2f(v0[4]); a5 += b2f(v0[5]); a6 += b2f(v0[6]); a7 += b2f(v0[7]);
            }
            o[0] = f2b(a0); o[1] = f2b(a1); o[2] = f2b(a2); o[3] = f2b(a3);
            o[4] = f2b(a4); o[5] = f2b(a5); o[6] = f2b(a6); o[7] = f2b(a7);
        } else {
            o = ushort8v{0, 0, 0, 0, 0, 0, 0, 0};
        }
        *(ushort8v*)&As[nloc * K + ((lane * 8) ^ ((nloc & 7) * 8))] = o;
    }
    __syncthreads();

    // ---- phase B: MFMA over LDS A (64 rows), global Bt ----
    const int wr = w & 1, wc = w >> 1;
    const int r16 = l & 15, kg = l >> 4;
    f32x4 acc[2][4] = {};
#pragma unroll
    for (int k0 = 0; k0 < K; k0 += 32) {
        int k = k0 + kg * 8;
        short8v a[2], b[4];
#pragma unroll
        for (int m = 0; m < 2; ++m) {
            int row = wr * 32 + m * 16 + r16;
            a[m] = *(const short8v*)&As[row * K + (k ^ ((row & 7) * 8))];
        }
#pragma unroll
        for (int n = 0; n < 4; ++n)
            b[n] = *(const short8v*)&Bt[(size_t)(wc * 64 + n * 16 + r16) * K + k];
#pragma unroll
        for (int m = 0; m < 2; ++m)
#pragma unroll
            for (int n = 0; n < 4; ++n)
                acc[m][n] = __builtin_amdgcn_mfma_f32_16x16x32_bf16(a[m], b[n], acc[m][n], 0, 0, 0);
    }
    float bv[4];
#pragma unroll
    for (int n = 0; n < 4; ++n) bv[n] = bias[wc * 64 + n * 16 + r16];
#pragma unroll
    for (int m = 0; m < 2; ++m) {
#pragma unroll
        for (int j = 0; j < 4; ++j) {
            int row = R0 + wr * 32 + m * 16 + kg * 4 + j;
            if (row >= NNODES) continue;
            float dr = dis[row];
            float os = scale_out ? dr : 1.0f;
#pragma unroll
            for (int n = 0; n < 4; ++n) {
                float v = fmaxf(dr * acc[m][n][j] + bv[n], 0.f) * os;
                hout[(size_t)row * HID + wc * 64 + n * 16 + r16] = f2b(v);
            }
        }
    }
}

// ---------------- graph boundaries from sorted batch ----------------
__global__ __launch_bounds__(256) void graph_bounds(const int* __restrict__ batch, int* __restrict__ gstart) {
    int i = blockIdx.x * 256 + threadIdx.x;
    if (i >= NNODES) return;
    int b = batch[i];
    if (i == 0) {
        for (int g = 0; g <= b; ++g) gstart[g] = 0;
    } else {
        int pb = batch[i - 1];
        for (int g = pb + 1; g <= b; ++g) gstart[g] = i;
    }
    if (i == NNODES - 1) {
        for (int g = b + 1; g <= NGRAPHS; ++g) gstart[g] = NNODES;
    }
}

// ---------------- mean pool: sliced, atomic partial sums (h is bf16) ----------------
__global__ __launch_bounds__(HID) void pool_partial(const ushort* __restrict__ h, const int* __restrict__ gstart,
                                                    float* __restrict__ z) {
    int g = blockIdx.x;
    int s = blockIdx.y;
    int t = threadIdx.x;
    int n0 = gstart[g], n1 = gstart[g + 1];
    int cnt = n1 - n0;
    if (cnt <= 0) return;
    int len = (cnt + NSLICE - 1) / NSLICE;
    int a = n0 + s * len;
    int b = a + len < n1 ? a + len : n1;
    if (a >= b) return;
    float acc = 0.f;
    for (int n = a; n < b; ++n) acc += b2f(h[(size_t)n * HID + t]);
    atomicAdd(&z[g * ZSTR + t], acc);
}

__global__ __launch_bounds__(HID) void pool_finalize(const int* __restrict__ gstart, const float* __restrict__ hlr,
                                                     const float* __restrict__ stdv, float* __restrict__ z) {
    int g = blockIdx.x;
    int t = threadIdx.x;
    int cnt = gstart[g + 1] - gstart[g];
    float inv = 1.f / (float)(cnt > 0 ? cnt : 1);
    z[g * ZSTR + t] *= inv;
    if (t == 0) {
        z[g * ZSTR + HID] = hlr[g];
        z[g * ZSTR + HID + 1] = stdv[g];
    }
}

// ---------------- FC head: relu(z @ fcW0 + fcb0) @ fcW1 + fcb1 ----------------
__global__ __launch_bounds__(HID) void fc_k(const float* __restrict__ z, const float* __restrict__ fcW0,
                                            const float* __restrict__ fcb0, const float* __restrict__ fcW1,
                                            const float* __restrict__ fcb1, float* __restrict__ out) {
    __shared__ float zs[ZSTR];
    __shared__ float z2[HID];
    int g = blockIdx.x;
    int t = threadIdx.x;
    zs[t] = z[g * ZSTR + t];
    if (t < 2) zs[HID + t] = z[g * ZSTR + HID + t];
    __syncthreads();
    float acc = fcb0[t];
    for (int k = 0; k < ZSTR; ++k) acc += zs[k] * fcW0[k * HID + t];
    z2[t] = fmaxf(acc, 0.f);
    __syncthreads();
    if (t < INCH) {
        float acc2 = fcb1[t];
        for (int k = 0; k < HID; ++k) acc2 += z2[k] * fcW1[k * INCH + t];
        out[g * INCH + t] = acc2;
    }
}

extern "C" void kernel_launch(void* const* d_in, const int* in_sizes, int n_in,
                              void* d_out, int out_size, void* d_ws, size_t ws_size,
                              hipStream_t stream) {
    const float* x = (const float*)d_in[0];
    const int* ei = (const int*)d_in[1];
    const int* src = ei;
    const int* dst = ei + NEDGES;
    const int* batch = (const int*)d_in[2];
    const float* hlr = (const float*)d_in[3];
    const float* stdv = (const float*)d_in[4];
    const float* W0 = (const float*)d_in[5];
    const float* b0 = (const float*)d_in[6];
    const float* W1 = (const float*)d_in[7];
    const float* b1 = (const float*)d_in[8];
    const float* W2 = (const float*)d_in[9];
    const float* b2 = (const float*)d_in[10];
    const float* fcW0 = (const float*)d_in[11];
    const float* fcb0 = (const float*)d_in[12];
    const float* fcW1 = (const float*)d_in[13];
    const float* fcb1 = (const float*)d_in[14];
    float* out = (float*)d_out;

    char* p = (char*)d_ws;
    auto alloc = [&](size_t bytes) -> char* {
        char* r = p;
        p += (bytes + 255) & ~(size_t)255;
        return r;
    };
    ushort* xb = (ushort*)alloc(sizeof(ushort) * (size_t)NNODES * INCH);
    ushort* h = (ushort*)alloc(sizeof(ushort) * (size_t)NNODES * HID);
    ushort* hb = (ushort*)alloc(sizeof(ushort) * (size_t)NNODES * HID);
    ushort* Wt0 = (ushort*)alloc(sizeof(ushort) * HID * INCH);
    ushort* Wt1 = (ushort*)alloc(sizeof(ushort) * HID * HID);
    ushort* Wt2 = (ushort*)alloc(sizeof(ushort) * HID * HID);
    float* dis = (float*)alloc(sizeof(float) * NNODES);
    int* deg = (int*)alloc(sizeof(int) * NNODES);
    int* row_ptr = (int*)alloc(sizeof(int) * (NNODES + 1));
    unsigned char* pwn = (unsigned char*)alloc(sizeof(unsigned char) * NEDGES);
    ushort* csr_src = (ushort*)alloc(sizeof(ushort) * NEDGES);
    int* bsum = (int*)alloc(sizeof(int) * 128);
    int* gstart = (int*)alloc(sizeof(int) * (NGRAPHS + 1));
    float* z = (float*)alloc(sizeof(float) * NGRAPHS * ZSTR);
    (void)ws_size; (void)in_sizes; (void)n_in; (void)out_size;

    const int eblocks = (NEDGES + 255) / 256;

    hipMemsetAsync(deg, 0, sizeof(int) * NNODES, stream);
    fill_pre<<<eblocks, 256, 0, stream>>>(dst, deg, pwn);
    dis_kernel<<<(NNODES + 255) / 256, 256, 0, stream>>>(deg, dis);
    scan1<<<SCAN_NB, SCAN_B, 0, stream>>>(deg, row_ptr, bsum);
    scan2<<<1, 128, 0, stream>>>(bsum);
    scan3<<<SCAN_NB, SCAN_B, 0, stream>>>(row_ptr, bsum);
    fill_scatter<<<eblocks, 256, 0, stream>>>(src, dst, pwn, row_ptr, csr_src);

    // conversions (x' = dis * x)
    xcvt<<<(NNODES * INCH / 4 + 255) / 256, 256, 0, stream>>>((const float4*)x, dis, (ushort4*)xb,
                                                              NNODES * INCH / 4);
    wcvt<<<(INCH * HID + 255) / 256, 256, 0, stream>>>(W0, Wt0, INCH, HID);
    wcvt<<<(HID * HID + 255) / 256, 256, 0, stream>>>(W1, Wt1, HID, HID);
    wcvt<<<(HID * HID + 255) / 256, 256, 0, stream>>>(W2, Wt2, HID, HID);

    const int gblocks = (NNODES + 63) / 64;
    gcn_fused<INCH><<<gblocks, 512, 0, stream>>>(xb, row_ptr, csr_src, Wt0, b0, dis, h, 1);
    gcn_fused<HID><<<gblocks, 512, 0, stream>>>(h, row_ptr, csr_src, Wt1, b1, dis, hb, 1);
    gcn_fused<HID><<<gblocks, 512, 0, stream>>>(hb, row_ptr, csr_src, Wt2, b2, dis, h, 0);

    graph_bounds<<<(NNODES + 255) / 256, 256, 0, stream>>>(batch, gstart);
    hipMemsetAsync(z, 0, sizeof(float) * NGRAPHS * ZSTR, stream);
    dim3 pgrid(NGRAPHS, NSLICE);
    pool_partial<<<pgrid, HID, 0, stream>>>(h, gstart, z);
    pool_finalize<<<NGRAPHS, HID, 0, stream>>>(gstart, hlr, stdv, z);
    fc_k<<<NGRAPHS, HID, 0, stream>>>(z, fcW0, fcb0, fcW1, fcb1, out);
}

// Round 17
// 319.331 us; speedup vs baseline: 4.4378x; 1.1978x over previous
//
#include <hip/hip_runtime.h>

#define NNODES 50000
#define NEDGES 800000
#define NGRAPHS 64
#define INCH 128
#define HID 256
#define ZSTR (HID + 2)
#define SCAN_B 512
#define SCAN_NB ((NNODES + SCAN_B - 1) / SCAN_B)   // 98

typedef __attribute__((ext_vector_type(8))) short short8v;
typedef __attribute__((ext_vector_type(8))) unsigned short ushort8v;
typedef __attribute__((ext_vector_type(4))) float f32x4;

__device__ inline ushort f2b(float f) {
    union { float f; unsigned u; } v; v.f = f;
    unsigned r = (v.u + 0x7FFFu + ((v.u >> 16) & 1u)) >> 16;
    return (ushort)r;
}
__device__ inline float b2f(ushort b) {
    union { unsigned u; float f; } v; v.u = ((unsigned)b) << 16;
    return v.f;
}

// ---------------- degree + within-node position in ONE atomic pass ----------------
__global__ __launch_bounds__(256) void fill_pre(const int* __restrict__ dst, int* __restrict__ deg,
                                                unsigned char* __restrict__ pwn) {
    int e = blockIdx.x * 256 + threadIdx.x;
    if (e < NEDGES) pwn[e] = (unsigned char)atomicAdd(&deg[dst[e]], 1);
}

__global__ __launch_bounds__(256) void dis_kernel(const int* __restrict__ deg, float* __restrict__ dis) {
    int i = blockIdx.x * 256 + threadIdx.x;
    if (i < NNODES) dis[i] = rsqrtf((float)deg[i] + 1.0f);
}

// ---------------- scan (row_ptr from deg) ----------------
__global__ __launch_bounds__(SCAN_B) void scan1(const int* __restrict__ deg, int* __restrict__ row_ptr,
                                                int* __restrict__ bsum) {
    __shared__ int s[SCAN_B];
    int t = threadIdx.x;
    int i = blockIdx.x * SCAN_B + t;
    int v = (i < NNODES) ? deg[i] : 0;
    s[t] = v;
    __syncthreads();
    for (int off = 1; off < SCAN_B; off <<= 1) {
        int x = (t >= off) ? s[t - off] : 0;
        __syncthreads();
        if (t >= off) s[t] += x;
        __syncthreads();
    }
    if (i < NNODES) row_ptr[i + 1] = s[t];
    if (t == SCAN_B - 1) bsum[blockIdx.x] = s[t];
}

__global__ __launch_bounds__(128) void scan2(int* __restrict__ bsum) {
    __shared__ int s[128];
    int t = threadIdx.x;
    int v = (t < SCAN_NB) ? bsum[t] : 0;
    s[t] = v;
    __syncthreads();
    for (int off = 1; off < 128; off <<= 1) {
        int x = (t >= off) ? s[t - off] : 0;
        __syncthreads();
        if (t >= off) s[t] += x;
        __syncthreads();
    }
    if (t < SCAN_NB) bsum[t] = s[t];
}

__global__ __launch_bounds__(SCAN_B) void scan3(int* __restrict__ row_ptr, const int* __restrict__ bsum) {
    int b = blockIdx.x, t = threadIdx.x;
    int i = b * SCAN_B + t;
    if (i == 0) row_ptr[0] = 0;
    if (i < NNODES && b > 0) row_ptr[i + 1] += bsum[b - 1];
}

// ---------------- atomic-free CSR scatter, single pass, ushort payload ----------------
__global__ __launch_bounds__(256) void fill_scatter(const int* __restrict__ src, const int* __restrict__ dst,
                                                    const unsigned char* __restrict__ pwn,
                                                    const int* __restrict__ row_ptr,
                                                    ushort* __restrict__ csr_src) {
    int e = blockIdx.x * 256 + threadIdx.x;
    if (e >= NEDGES) return;
    int d = dst[e];
    csr_src[row_ptr[d] + pwn[e]] = (ushort)src[e];
}

// ---------------- x' = dis * x -> bf16 ----------------
__global__ __launch_bounds__(256) void xcvt(const float4* __restrict__ x, const float* __restrict__ dis,
                                            ushort4* __restrict__ xb, int n4) {
    int i = blockIdx.x * 256 + threadIdx.x;
    if (i >= n4) return;
    float d = dis[i >> 5];   // 32 float4 per node (128 ch)
    float4 v = x[i];
    ushort4 o;
    o.x = f2b(d * v.x); o.y = f2b(d * v.y); o.z = f2b(d * v.z); o.w = f2b(d * v.w);
    xb[i] = o;
}

// W[K x N] fp32 -> Wt[N x K] bf16
__global__ __launch_bounds__(256) void wcvt(const float* __restrict__ W, ushort* __restrict__ Wt, int K, int N) {
    int i = blockIdx.x * 256 + threadIdx.x;
    if (i >= K * N) return;
    int k = i / N, n = i - k * N;
    Wt[n * K + k] = f2b(W[i]);
}

// ---------------- fused GCN layer: gather-sum into LDS, then MFMA GEMM + epilogue ----------------
// hin: bf16 [N x K] pre-scaled by dis; Bt: bf16 [256 x K]; hout: bf16 [N x 256]
// hout_r = relu(dis_r * (S @ W)_r + bias) * (scale_out ? dis_r : 1),  S_r = hin_r + sum_{j->r} hin_j
// POOL variant (last layer): skip hout write entirely; register-reduce per-graph partial sums
// (128 sorted rows span <=2 graphs), 8 LDS atomics/thread into z_loc[2][256], one global
// atomicAdd per (graph, channel) per block.
template <int K, bool POOL>
__global__ __launch_bounds__(512, 4) void gcn_fused(const ushort* __restrict__ hin,
                                                    const int* __restrict__ row_ptr,
                                                    const ushort* __restrict__ csr_src,
                                                    const ushort* __restrict__ Bt,
                                                    const float* __restrict__ bias,
                                                    const float* __restrict__ dis,
                                                    ushort* __restrict__ hout, int scale_out,
                                                    const int* __restrict__ batch, float* __restrict__ z) {
    __shared__ ushort As[128 * K];   // XOR-swizzled: 16B granule g of row r lives at g^(r&7)
    __shared__ float z_loc[2][HID];
    const int tid = threadIdx.x;
    const int w = tid >> 6, l = tid & 63;
    const int R0 = blockIdx.x * 128;

    if (POOL) {   // zero the pool tile (512 threads cover 2x256 exactly)
        z_loc[tid >> 8][tid & 255] = 0.f;
    }

    // ---- phase A: gather-sum 128 rows into LDS ----
    constexpr int CHL = K / 8;        // lanes per node (8 ch each)
    constexpr int NPW = 64 / CHL;     // nodes per wave pass
    const int sub = l / CHL;
    const int lane = l - sub * CHL;
    const ushort* hp = hin + lane * 8;
#pragma unroll
    for (int it = 0; it < 128 / (8 * NPW); ++it) {
        int nloc = (it * 8 + w) * NPW + sub;
        int node = R0 + nloc;
        ushort8v o;
        if (node < NNODES) {
            ushort8v sv = *(const ushort8v*)&hp[(size_t)node * K];
            float a0 = b2f(sv[0]), a1 = b2f(sv[1]), a2 = b2f(sv[2]), a3 = b2f(sv[3]);
            float a4 = b2f(sv[4]), a5 = b2f(sv[5]), a6 = b2f(sv[6]), a7 = b2f(sv[7]);
            int e = row_ptr[node], e1 = row_ptr[node + 1];
            for (; e + 7 < e1; e += 8) {
                ushort8v v[8];
#pragma unroll
                for (int u = 0; u < 8; ++u) v[u] = *(const ushort8v*)&hp[(size_t)csr_src[e + u] * K];
#pragma unroll
                for (int u = 0; u < 8; ++u) {
                    a0 += b2f(v[u][0]); a1 += b2f(v[u][1]); a2 += b2f(v[u][2]); a3 += b2f(v[u][3]);
                    a4 += b2f(v[u][4]); a5 += b2f(v[u][5]); a6 += b2f(v[u][6]); a7 += b2f(v[u][7]);
                }
            }
            for (; e < e1; ++e) {
                ushort8v v0 = *(const ushort8v*)&hp[(size_t)csr_src[e] * K];
                a0 += b2f(v0[0]); a1 += b2f(v0[1]); a2 += b2f(v0[2]); a3 += b2f(v0[3]);
                a4 += b2f(v0[4]); a5 += b2f(v0[5]); a6 += b2f(v0[6]); a7 += b2f(v0[7]);
            }
            o[0] = f2b(a0); o[1] = f2b(a1); o[2] = f2b(a2); o[3] = f2b(a3);
            o[4] = f2b(a4); o[5] = f2b(a5); o[6] = f2b(a6); o[7] = f2b(a7);
        } else {
            o = ushort8v{0, 0, 0, 0, 0, 0, 0, 0};
        }
        *(ushort8v*)&As[nloc * K + ((lane * 8) ^ ((nloc & 7) * 8))] = o;
    }
    __syncthreads();

    // ---- phase B: MFMA over LDS A, global Bt ----
    const int wr = w >> 2, wc = w & 3;
    const int r16 = l & 15, kg = l >> 4;
    f32x4 acc[4][4] = {};
#pragma unroll
    for (int k0 = 0; k0 < K; k0 += 32) {
        int k = k0 + kg * 8;
        short8v a[4], b[4];
#pragma unroll
        for (int m = 0; m < 4; ++m) {
            int row = wr * 64 + m * 16 + r16;
            a[m] = *(const short8v*)&As[row * K + (k ^ ((row & 7) * 8))];
        }
#pragma unroll
        for (int n = 0; n < 4; ++n)
            b[n] = *(const short8v*)&Bt[(size_t)(wc * 64 + n * 16 + r16) * K + k];
#pragma unroll
        for (int m = 0; m < 4; ++m)
#pragma unroll
            for (int n = 0; n < 4; ++n)
                acc[m][n] = __builtin_amdgcn_mfma_f32_16x16x32_bf16(a[m], b[n], acc[m][n], 0, 0, 0);
    }
    float bv[4];
#pragma unroll
    for (int n = 0; n < 4; ++n) bv[n] = bias[wc * 64 + n * 16 + r16];

    if (!POOL) {
#pragma unroll
        for (int m = 0; m < 4; ++m) {
#pragma unroll
            for (int j = 0; j < 4; ++j) {
                int row = R0 + wr * 64 + m * 16 + kg * 4 + j;
                if (row >= NNODES) continue;
                float dr = dis[row];
                float os = scale_out ? dr : 1.0f;
#pragma unroll
                for (int n = 0; n < 4; ++n) {
                    float v = fmaxf(dr * acc[m][n][j] + bv[n], 0.f) * os;
                    hout[(size_t)row * HID + wc * 64 + n * 16 + r16] = f2b(v);
                }
            }
        }
    } else {
        const int g0 = batch[R0];
        float psum[2][4] = {{0.f, 0.f, 0.f, 0.f}, {0.f, 0.f, 0.f, 0.f}};
#pragma unroll
        for (int m = 0; m < 4; ++m) {
#pragma unroll
            for (int j = 0; j < 4; ++j) {
                int row = R0 + wr * 64 + m * 16 + kg * 4 + j;
                if (row >= NNODES) continue;
                float dr = dis[row];
                int slot = batch[row] - g0;
#pragma unroll
                for (int n = 0; n < 4; ++n) {
                    float v = fmaxf(dr * acc[m][n][j] + bv[n], 0.f);
                    if (slot <= 1) {
                        psum[slot][n] += v;
                    } else {   // pathological tiny-graph fallback (never expected)
                        atomicAdd(&z[(size_t)(g0 + slot) * ZSTR + wc * 64 + n * 16 + r16], v);
                    }
                }
            }
        }
#pragma unroll
        for (int s = 0; s < 2; ++s)
#pragma unroll
            for (int n = 0; n < 4; ++n)
                if (psum[s][n] != 0.f) atomicAdd(&z_loc[s][wc * 64 + n * 16 + r16], psum[s][n]);
        __syncthreads();
        int last = R0 + 127;
        if (last > NNODES - 1) last = NNODES - 1;
        const int g_last = batch[last];
        const int s = tid >> 8;          // 0 or 1
        const int ch = tid & 255;
        if (g0 + s <= g_last && g0 + s < NGRAPHS) {
            float v = z_loc[s][ch];
            if (v != 0.f) atomicAdd(&z[(size_t)(g0 + s) * ZSTR + ch], v);
        }
    }
}

// ---------------- graph boundaries from sorted batch ----------------
__global__ __launch_bounds__(256) void graph_bounds(const int* __restrict__ batch, int* __restrict__ gstart) {
    int i = blockIdx.x * 256 + threadIdx.x;
    if (i >= NNODES) return;
    int b = batch[i];
    if (i == 0) {
        for (int g = 0; g <= b; ++g) gstart[g] = 0;
    } else {
        int pb = batch[i - 1];
        for (int g = pb + 1; g <= b; ++g) gstart[g] = i;
    }
    if (i == NNODES - 1) {
        for (int g = b + 1; g <= NGRAPHS; ++g) gstart[g] = NNODES;
    }
}

__global__ __launch_bounds__(HID) void pool_finalize(const int* __restrict__ gstart, const float* __restrict__ hlr,
                                                     const float* __restrict__ stdv, float* __restrict__ z) {
    int g = blockIdx.x;
    int t = threadIdx.x;
    int cnt = gstart[g + 1] - gstart[g];
    float inv = 1.f / (float)(cnt > 0 ? cnt : 1);
    z[g * ZSTR + t] *= inv;
    if (t == 0) {
        z[g * ZSTR + HID] = hlr[g];
        z[g * ZSTR + HID + 1] = stdv[g];
    }
}

// ---------------- FC head: relu(z @ fcW0 + fcb0) @ fcW1 + fcb1 ----------------
__global__ __launch_bounds__(HID) void fc_k(const float* __restrict__ z, const float* __restrict__ fcW0,
                                            const float* __restrict__ fcb0, const float* __restrict__ fcW1,
                                            const float* __restrict__ fcb1, float* __restrict__ out) {
    __shared__ float zs[ZSTR];
    __shared__ float z2[HID];
    int g = blockIdx.x;
    int t = threadIdx.x;
    zs[t] = z[g * ZSTR + t];
    if (t < 2) zs[HID + t] = z[g * ZSTR + HID + t];
    __syncthreads();
    float acc = fcb0[t];
    for (int k = 0; k < ZSTR; ++k) acc += zs[k] * fcW0[k * HID + t];
    z2[t] = fmaxf(acc, 0.f);
    __syncthreads();
    if (t < INCH) {
        float acc2 = fcb1[t];
        for (int k = 0; k < HID; ++k) acc2 += z2[k] * fcW1[k * INCH + t];
        out[g * INCH + t] = acc2;
    }
}

extern "C" void kernel_launch(void* const* d_in, const int* in_sizes, int n_in,
                              void* d_out, int out_size, void* d_ws, size_t ws_size,
                              hipStream_t stream) {
    const float* x = (const float*)d_in[0];
    const int* ei = (const int*)d_in[1];
    const int* src = ei;
    const int* dst = ei + NEDGES;
    const int* batch = (const int*)d_in[2];
    const float* hlr = (const float*)d_in[3];
    const float* stdv = (const float*)d_in[4];
    const float* W0 = (const float*)d_in[5];
    const float* b0 = (const float*)d_in[6];
    const float* W1 = (const float*)d_in[7];
    const float* b1 = (const float*)d_in[8];
    const float* W2 = (const float*)d_in[9];
    const float* b2 = (const float*)d_in[10];
    const float* fcW0 = (const float*)d_in[11];
    const float* fcb0 = (const float*)d_in[12];
    const float* fcW1 = (const float*)d_in[13];
    const float* fcb1 = (const float*)d_in[14];
    float* out = (float*)d_out;

    char* p = (char*)d_ws;
    auto alloc = [&](size_t bytes) -> char* {
        char* r = p;
        p += (bytes + 255) & ~(size_t)255;
        return r;
    };
    ushort* xb = (ushort*)alloc(sizeof(ushort) * (size_t)NNODES * INCH);
    ushort* h = (ushort*)alloc(sizeof(ushort) * (size_t)NNODES * HID);
    ushort* hb = (ushort*)alloc(sizeof(ushort) * (size_t)NNODES * HID);
    ushort* Wt0 = (ushort*)alloc(sizeof(ushort) * HID * INCH);
    ushort* Wt1 = (ushort*)alloc(sizeof(ushort) * HID * HID);
    ushort* Wt2 = (ushort*)alloc(sizeof(ushort) * HID * HID);
    float* dis = (float*)alloc(sizeof(float) * NNODES);
    int* deg = (int*)alloc(sizeof(int) * NNODES);
    int* row_ptr = (int*)alloc(sizeof(int) * (NNODES + 1));
    unsigned char* pwn = (unsigned char*)alloc(sizeof(unsigned char) * NEDGES);
    ushort* csr_src = (ushort*)alloc(sizeof(ushort) * NEDGES);
    int* bsum = (int*)alloc(sizeof(int) * 128);
    int* gstart = (int*)alloc(sizeof(int) * (NGRAPHS + 1));
    float* z = (float*)alloc(sizeof(float) * NGRAPHS * ZSTR);
    (void)ws_size; (void)in_sizes; (void)n_in; (void)out_size;

    const int eblocks = (NEDGES + 255) / 256;

    hipMemsetAsync(deg, 0, sizeof(int) * NNODES, stream);
    hipMemsetAsync(z, 0, sizeof(float) * NGRAPHS * ZSTR, stream);
    fill_pre<<<eblocks, 256, 0, stream>>>(dst, deg, pwn);
    dis_kernel<<<(NNODES + 255) / 256, 256, 0, stream>>>(deg, dis);
    scan1<<<SCAN_NB, SCAN_B, 0, stream>>>(deg, row_ptr, bsum);
    scan2<<<1, 128, 0, stream>>>(bsum);
    scan3<<<SCAN_NB, SCAN_B, 0, stream>>>(row_ptr, bsum);
    fill_scatter<<<eblocks, 256, 0, stream>>>(src, dst, pwn, row_ptr, csr_src);

    // conversions (x' = dis * x)
    xcvt<<<(NNODES * INCH / 4 + 255) / 256, 256, 0, stream>>>((const float4*)x, dis, (ushort4*)xb,
                                                              NNODES * INCH / 4);
    wcvt<<<(INCH * HID + 255) / 256, 256, 0, stream>>>(W0, Wt0, INCH, HID);
    wcvt<<<(HID * HID + 255) / 256, 256, 0, stream>>>(W1, Wt1, HID, HID);
    wcvt<<<(HID * HID + 255) / 256, 256, 0, stream>>>(W2, Wt2, HID, HID);

    const int gblocks = (NNODES + 127) / 128;
    gcn_fused<INCH, false><<<gblocks, 512, 0, stream>>>(xb, row_ptr, csr_src, Wt0, b0, dis, h, 1, batch, z);
    gcn_fused<HID, false><<<gblocks, 512, 0, stream>>>(h, row_ptr, csr_src, Wt1, b1, dis, hb, 1, batch, z);
    // layer 2: pool fused into epilogue, no h write
    gcn_fused<HID, true><<<gblocks, 512, 0, stream>>>(hb, row_ptr, csr_src, Wt2, b2, dis, h, 0, batch, z);

    graph_bounds<<<(NNODES + 255) / 256, 256, 0, stream>>>(batch, gstart);
    pool_finalize<<<NGRAPHS, HID, 0, stream>>>(gstart, hlr, stdv, z);
    fc_k<<<NGRAPHS, HID, 0, stream>>>(z, fcW0, fcb0, fcW1, fcb1, out);
}